// Round 19
// baseline (271.954 us; speedup 1.0000x reference)
//
#include <hip/hip_runtime.h>
#include <hip/hip_bf16.h>
#include <stdint.h>

#define DIN   1024
#define DOUT  1024
#define NHEAD 16
#define HDIM  64
#define SEQL  2048
#define BSZ   4
#define MTOT  (BSZ*SEQL)   // 8192
#define KDIM  1024

typedef __bf16 bf16x8 __attribute__((ext_vector_type(8)));
typedef float  f32x4  __attribute__((ext_vector_type(4)));

__device__ __forceinline__ f32x4 mfma16(bf16x8 a, bf16x8 b, f32x4 c) {
    return __builtin_amdgcn_mfma_f32_16x16x32_bf16(a, b, c, 0, 0, 0);
}

__device__ __forceinline__ void gl_lds16(const void* gsrc, void* ldst) {
    __builtin_amdgcn_global_load_lds(
        (const __attribute__((address_space(1))) uint32_t*)gsrc,
        (__attribute__((address_space(3))) uint32_t*)ldst, 16, 0, 0);
}

// hardware exp2: single v_exp_f32 (attn only)
#if __has_builtin(__builtin_amdgcn_exp2f)
__device__ __forceinline__ float fexp2(float x) { return __builtin_amdgcn_exp2f(x); }
#else
__device__ __forceinline__ float fexp2(float x) { return exp2f(x); }
#endif

// pack 2 f32 -> bf16x2 (attn only)
__device__ __forceinline__ unsigned int cvtpk(float lo, float hi) {
    unsigned int r;
    asm("v_cvt_pk_bf16_f32 %0, %1, %2" : "=v"(r) : "v"(lo), "v"(hi));
    return r;
}

__device__ __forceinline__ unsigned short f2bf(float f) {
    union { __hip_bfloat16 h; unsigned short u; } cv;
    cv.h = __float2bfloat16(f);
    return cv.u;
}

// ---------------- fp32 -> bf16 elementwise (vectorized) ----------------
__global__ void cvt_bf16(const float4* __restrict__ in, ushort4* __restrict__ out, int n4) {
    int idx = blockIdx.x * blockDim.x + threadIdx.x;
    int stride = gridDim.x * blockDim.x;
    for (int i = idx; i < n4; i += stride) {
        float4 v = in[i];
        ushort4 o;
        o.x = f2bf(v.x); o.y = f2bf(v.y); o.z = f2bf(v.z); o.w = f2bf(v.w);
        out[i] = o;
    }
}

// ---- transpose + convert 3x W[1024][1024] f32 -> one Wt3[3072][1024] bf16 ----
__global__ void transpose_cvt3(const float* __restrict__ W0, const float* __restrict__ W1,
                               const float* __restrict__ W2, __hip_bfloat16* __restrict__ Wt3) {
    __shared__ __hip_bfloat16 t[32][33];
    const int tx = threadIdx.x, ty = threadIdx.y;   // (32, 8)
    const int bx = blockIdx.x, by = blockIdx.y, z = blockIdx.z;
    const float* W = (z == 0) ? W0 : (z == 1) ? W1 : W2;
    __hip_bfloat16* Wt = Wt3 + (size_t)z * DOUT * DIN;
#pragma unroll
    for (int r = 0; r < 4; ++r)
        t[ty + 8*r][tx] = __float2bfloat16(W[(size_t)(by*32 + ty + 8*r) * DOUT + bx*32 + tx]);
    __syncthreads();
#pragma unroll
    for (int r = 0; r < 4; ++r)
        Wt[(size_t)(bx*32 + ty + 8*r) * DIN + by*32 + tx] = t[tx][ty + 8*r];
}

__global__ void transpose_cvt(const float* __restrict__ W, __hip_bfloat16* __restrict__ Wt) {
    __shared__ __hip_bfloat16 t[32][33];
    const int tx = threadIdx.x, ty = threadIdx.y;
    const int bx = blockIdx.x, by = blockIdx.y;
#pragma unroll
    for (int r = 0; r < 4; ++r)
        t[ty + 8*r][tx] = __float2bfloat16(W[(size_t)(by*32 + ty + 8*r) * DOUT + bx*32 + tx]);
    __syncthreads();
#pragma unroll
    for (int r = 0; r < 4; ++r)
        Wt[(size_t)(bx*32 + ty + 8*r) * DIN + by*32 + tx] = t[tx][ty + 8*r];
}

// ---------------- 128x128-tile MFMA GEMM (256 threads, 4 waves, BK=32; R11/R16 form) ----------------
template <int EPI>
__global__ __launch_bounds__(256)
void gemm_mfma(const __hip_bfloat16* __restrict__ A,
               const __hip_bfloat16* __restrict__ Bt,
               const float* __restrict__ b0, const float* __restrict__ b1,
               void* __restrict__ o0, void* __restrict__ o1,
               float scale)
{
    __shared__ alignas(16) __hip_bfloat16 As[2][4][128][8];
    __shared__ alignas(16) __hip_bfloat16 Bs[2][4][128][8];

    const int tid  = threadIdx.x;
    const int w    = tid >> 6;
    const int lane = tid & 63;
    const int g    = lane >> 4;
    const int r    = lane & 15;
    const int wr   = w >> 1, wc = w & 1;

    const int row0 = blockIdx.y * 128;
    const int col0 = blockIdx.x * 128;

    f32x4 acc[4][4];
#pragma unroll
    for (int m = 0; m < 4; ++m)
#pragma unroll
        for (int n = 0; n < 4; ++n) acc[m][n] = (f32x4)0.0f;

    auto stage = [&](int buf, int kt) {
        const __hip_bfloat16* ga = A  + (size_t)(row0 + lane) * KDIM + kt*32 + 8*w;
        const __hip_bfloat16* gb = Bt + (size_t)(col0 + lane) * KDIM + kt*32 + 8*w;
        gl_lds16(ga,            &As[buf][w][0][0]);
        gl_lds16(ga + 64*KDIM,  &As[buf][w][64][0]);
        gl_lds16(gb,            &Bs[buf][w][0][0]);
        gl_lds16(gb + 64*KDIM,  &Bs[buf][w][64][0]);
    };

    stage(0, 0);
    __syncthreads();

    const int NKT = KDIM / 32;
    for (int kt = 0; kt < NKT; ++kt) {
        const int cur = kt & 1;
        if (kt + 1 < NKT) stage(cur ^ 1, kt + 1);

        bf16x8 af[4], bfr[4];
#pragma unroll
        for (int m = 0; m < 4; ++m)
            af[m] = *reinterpret_cast<const bf16x8*>(&As[cur][g][64*wr + 16*m + r][0]);
#pragma unroll
        for (int n = 0; n < 4; ++n)
            bfr[n] = *reinterpret_cast<const bf16x8*>(&Bs[cur][g][64*wc + 16*n + r][0]);

#pragma unroll
        for (int m = 0; m < 4; ++m)
#pragma unroll
            for (int n = 0; n < 4; ++n) {
                if (EPI == 1) acc[m][n] = mfma16(af[m], bfr[n], acc[m][n]);  // C
                else          acc[m][n] = mfma16(bfr[n], af[m], acc[m][n]);  // C^T
            }

        __syncthreads();
    }

    if (EPI == 0) {
        const int slab = col0 >> 10;                    // block-uniform
        const float* bp = (slab == 0) ? b0 : b1;
        __hip_bfloat16* op = (__hip_bfloat16*)((slab == 0) ? o0 : o1);
        const float sc = (slab == 0) ? scale : 1.0f;
#pragma unroll
        for (int m = 0; m < 4; ++m) {
            const int rowg = row0 + 64*wr + 16*m + r;
            const int bb = rowg >> 11, sq = rowg & (SEQL-1);
#pragma unroll
            for (int n = 0; n < 4; ++n) {
                const int c2 = (col0 & 1023) + 64*wc + 16*n + 4*g;
                const int hh = c2 >> 6, dd = c2 & (HDIM-1);
                const float4 bv4 = *reinterpret_cast<const float4*>(&bp[c2]);
                ushort4 ov;
                ov.x = f2bf((acc[m][n][0] + bv4.x) * sc);
                ov.y = f2bf((acc[m][n][1] + bv4.y) * sc);
                ov.z = f2bf((acc[m][n][2] + bv4.z) * sc);
                ov.w = f2bf((acc[m][n][3] + bv4.w) * sc);
                *reinterpret_cast<ushort4*>(
                    &op[(((size_t)(bb*NHEAD + hh) * SEQL + sq) << 6) + dd]) = ov;
            }
        }
    } else if (EPI == 1) {
#pragma unroll
        for (int n = 0; n < 4; ++n) {
            const int colg = col0 + 64*wc + 16*n + r;
            const int hh = colg >> 6, dd = colg & (HDIM-1);
            const float bv_ = b0[colg];
#pragma unroll
            for (int m = 0; m < 4; ++m) {
                const int rowg0 = row0 + 64*wr + 16*m + 4*g;
                const int bb = rowg0 >> 11, sq0 = rowg0 & (SEQL-1);
                ushort4 ov;
                ov.x = f2bf(acc[m][n][0] + bv_);
                ov.y = f2bf(acc[m][n][1] + bv_);
                ov.z = f2bf(acc[m][n][2] + bv_);
                ov.w = f2bf(acc[m][n][3] + bv_);
                *reinterpret_cast<ushort4*>(
                    &((__hip_bfloat16*)o0)[((size_t)(bb*NHEAD + hh) * HDIM + dd) * SEQL + sq0]) = ov;
            }
        }
    } else {
#pragma unroll
        for (int m = 0; m < 4; ++m) {
            const int rowg = row0 + 64*wr + 16*m + r;
#pragma unroll
            for (int n = 0; n < 4; ++n) {
                const int colg0 = col0 + 64*wc + 16*n + 4*g;
                const float4 bv4 = *reinterpret_cast<const float4*>(&b0[colg0]);
                float4 ov;
                ov.x = acc[m][n][0] + bv4.x;
                ov.y = acc[m][n][1] + bv4.y;
                ov.z = acc[m][n][2] + bv4.z;
                ov.w = acc[m][n][3] + bv4.w;
                *reinterpret_cast<float4*>(&((float*)o0)[(size_t)rowg * DOUT + colg0]) = ov;
            }
        }
    }
}

// ---------------- causal flash attention (64 rows/wave, split-K, K-dbuf) ----------------
// Q,K: [B,H,S,64] bf16 (Q pre-scaled by log2e/8).  Vt: [B,H,64,S] bf16.
// ctx: [B,S,H*64] bf16.
// R17 structure (scatter-amortized m=4, split-K halves, XCD grid, pointer-bump,
// deferred softmax, fexp2/cvtpk) + K DOUBLE-BUFFER. Rationale: R17 is at
// 2 waves/SIMD (supply 2048 waves; VGPR 168) -- adding +32 VGPR for the K-dbuf
// keeps 2 waves/SIMD (512/200=2), so the ILP is occupancy-FREE (unlike R15,
// where the same change at m=2 crossed 3->2 waves/SIMD and regressed). Next-step
// K is in flight across this step's softmax+PV (~700 cyc at m=4).
__global__ __launch_bounds__(256)
void attn_fwd(const __hip_bfloat16* __restrict__ Q,
              const __hip_bfloat16* __restrict__ K,
              const __hip_bfloat16* __restrict__ Vt,
              __hip_bfloat16* __restrict__ ctx)
{
    __shared__ alignas(16) __hip_bfloat16 Ps[4][16][64];  // 8KB, per-wave, per-m reuse
    __shared__ alignas(16) f32x4 Om[2][64][16];           // 32KB merge buffer
    __shared__ float Ml[2][64][9];                        // m[4], l[4] (+pad)

    const int tid  = threadIdx.x;
    const int w    = tid >> 6;
    const int lane = tid & 63;
    const int g    = lane >> 4;
    const int r    = lane & 15;
    const int swz  = (r & 7) << 3;   // element-XOR within a 64-elt (128B) row
    const int pp   = w >> 1;         // pair index within block (0..1)
    const int half = w & 1;          // key-range half

    const int bh = blockIdx.x;       // XCD-local: id%8 == bh%8
    const int b  = bh >> 4, h = bh & 15;

    const __hip_bfloat16* Qh = Q  + (size_t)bh * SEQL * HDIM;
    const __hip_bfloat16* Kh = K  + (size_t)bh * SEQL * HDIM;
    const __hip_bfloat16* Vh = Vt + (size_t)bh * HDIM * SEQL;

    const int sp = blockIdx.y * 2 + pp;   // strip-pair id 0..15

#pragma unroll 1
    for (int ti = 0; ti < 2; ++ti) {
        const int strip = ti ? (31 - sp) : sp;
        const int qb = strip * 64;

        bf16x8 qf[4][2];
#pragma unroll
        for (int m = 0; m < 4; ++m)
#pragma unroll
            for (int hh = 0; hh < 2; ++hh)
                qf[m][hh] = *reinterpret_cast<const bf16x8*>(
                    Qh + (size_t)(qb + 16*m + r) * HDIM + 32*hh + 8*g);

        f32x4 o[4][4];
        float mrow[4], lrow[4];
#pragma unroll
        for (int m = 0; m < 4; ++m) {
#pragma unroll
            for (int n = 0; n < 4; ++n) o[m][n] = (f32x4)0.0f;
            mrow[m] = -1e30f; lrow[m] = 0.0f;
        }

        const int nst = strip + 1;
        const int ns2 = (nst + 1) >> 1;
        const int k0  = half ? ns2 : 0;
        const int k1  = half ? nst : ns2;

        // pointer-bump bases: per-lane, step-invariant immediate offsets.
        const __hip_bfloat16* kp01 = Kh + (size_t)(k0*64 + r) * HDIM + 8*g;
        const __hip_bfloat16* kp23 = kp01 + 32*HDIM;
        const __hip_bfloat16* vp0  = Vh + (size_t)r * SEQL + (size_t)k0*64 + 8*g;
        const __hip_bfloat16* vp1  = vp0 + (size_t)16*SEQL;
        const __hip_bfloat16* vp2  = vp0 + (size_t)32*SEQL;
        const __hip_bfloat16* vp3  = vp0 + (size_t)48*SEQL;

        bf16x8 kA[4][2], kB[4][2];

        auto loadK = [&](bf16x8 (&kf)[4][2]) __attribute__((always_inline)) {
#pragma unroll
            for (int hh = 0; hh < 2; ++hh) {
                kf[0][hh] = *reinterpret_cast<const bf16x8*>(kp01 + hh*32);
                kf[1][hh] = *reinterpret_cast<const bf16x8*>(kp01 + 16*HDIM + hh*32);
                kf[2][hh] = *reinterpret_cast<const bf16x8*>(kp23 + hh*32);
                kf[3][hh] = *reinterpret_cast<const bf16x8*>(kp23 + 16*HDIM + hh*32);
            }
            kp01 += 64*HDIM; kp23 += 64*HDIM;
        };

        auto step = [&](bf16x8 (&KC)[4][2], bf16x8 (&KN)[4][2], int kt)
                        __attribute__((always_inline)) {
            const int key0 = kt * 64;

            // V for THIS step (consumed after softmax); K for NEXT step (in
            // flight across this whole step's softmax+PV)
            bf16x8 vf[4][2];
#pragma unroll
            for (int hh = 0; hh < 2; ++hh) {
                vf[0][hh] = *reinterpret_cast<const bf16x8*>(vp0 + hh*32);
                vf[1][hh] = *reinterpret_cast<const bf16x8*>(vp1 + hh*32);
                vf[2][hh] = *reinterpret_cast<const bf16x8*>(vp2 + hh*32);
                vf[3][hh] = *reinterpret_cast<const bf16x8*>(vp3 + hh*32);
            }
            vp0 += 64; vp1 += 64; vp2 += 64; vp3 += 64;
            if (kt + 1 < k1) loadK(KN);

            const bool lastkt = (kt == nst - 1);

#pragma unroll
            for (int m = 0; m < 4; ++m) {
                // S^T[key = key0+16c+4g+j][qrow = qb+16m+r]
                f32x4 s[4];
                __builtin_amdgcn_s_setprio(1);
#pragma unroll
                for (int c = 0; c < 4; ++c) {
                    f32x4 t = (f32x4)0.0f;
                    t = mfma16(KC[c][0], qf[m][0], t);
                    t = mfma16(KC[c][1], qf[m][1], t);
                    s[c] = t;
                }
                __builtin_amdgcn_s_setprio(0);

                const int qrow = qb + 16*m + r;
                if (lastkt) {   // causal mask only in the boundary step
#pragma unroll
                    for (int c = 0; c < 4; ++c) {
                        const int kb = key0 + 16*c + 4*g;
#pragma unroll
                        for (int j = 0; j < 4; ++j)
                            if (kb + j > qrow) s[c][j] = -1e30f;
                    }
                }

                // lane-local max over this lane's 16 scores
                float t0 = fmaxf(fmaxf(s[0][0], s[0][1]), fmaxf(s[0][2], s[0][3]));
                float t1 = fmaxf(fmaxf(s[1][0], s[1][1]), fmaxf(s[1][2], s[1][3]));
                float t2 = fmaxf(fmaxf(s[2][0], s[2][1]), fmaxf(s[2][2], s[2][3]));
                float t3 = fmaxf(fmaxf(s[3][0], s[3][1]), fmaxf(s[3][2], s[3][3]));
                float pml = fmaxf(fmaxf(t0, t1), fmaxf(t2, t3));

                // deferred rescale: cross-lane reduce ONLY when triggered
                if (__any(pml > mrow[m] + 11.0f)) {
                    float pm = fmaxf(pml, __shfl_xor(pml, 16));
                    pm = fmaxf(pm, __shfl_xor(pm, 32));
                    const float mnew = fmaxf(mrow[m], pm);
                    const float fac  = fexp2(mrow[m] - mnew);
                    mrow[m] = mnew;
                    lrow[m] *= fac;
#pragma unroll
                    for (int n = 0; n < 4; ++n) o[m][n] *= fac;
                }

                float p[4][4];
#pragma unroll
                for (int c = 0; c < 4; ++c)
#pragma unroll
                    for (int j = 0; j < 4; ++j)
                        p[c][j] = fexp2(s[c][j] - mrow[m]);

                // lane-partial row sum (reduced across g-lanes once per strip)
                float u0 = (p[0][0] + p[0][1]) + (p[0][2] + p[0][3]);
                float u1 = (p[1][0] + p[1][1]) + (p[1][2] + p[1][3]);
                float u2 = (p[2][0] + p[2][1]) + (p[2][2] + p[2][3]);
                float u3 = (p[3][0] + p[3][1]) + (p[3][2] + p[3][3]);
                lrow[m] += (u0 + u1) + (u2 + u3);

                // pack P row-fragment -> swizzled ds_write (Ps reused per m)
#pragma unroll
                for (int c = 0; c < 4; ++c) {
                    uint2 pk;
                    pk.x = cvtpk(p[c][0], p[c][1]);
                    pk.y = cvtpk(p[c][2], p[c][3]);
                    *reinterpret_cast<uint2*>(&Ps[w][r][(16*c + 4*g) ^ swz]) = pk;
                }

                // P fragments (swizzled b128 reads) + PV as mfma(V^T, P^T)
                bf16x8 pf[2];
#pragma unroll
                for (int hh = 0; hh < 2; ++hh)
                    pf[hh] = *reinterpret_cast<const bf16x8*>(
                        &Ps[w][r][(32*hh + 8*g) ^ swz]);

                __builtin_amdgcn_s_setprio(1);
#pragma unroll
                for (int n = 0; n < 4; ++n) {
                    o[m][n] = mfma16(vf[n][0], pf[0], o[m][n]);
                    o[m][n] = mfma16(vf[n][1], pf[1], o[m][n]);
                }
                __builtin_amdgcn_s_setprio(0);
            }
        };

        loadK(kA);
        int kt = k0;
        while (kt < k1) {
            step(kA, kB, kt); if (++kt >= k1) break;
            step(kB, kA, kt); ++kt;
        }

        // reduce lane-partial lrow across the 4 g-lanes (once per strip)
#pragma unroll
        for (int m = 0; m < 4; ++m) {
            lrow[m] += __shfl_xor(lrow[m], 16);
            lrow[m] += __shfl_xor(lrow[m], 32);
        }

        // ----- split-K merge: half1 publishes partials, half0 merges + stores -----
        if (half) {
#pragma unroll
            for (int m = 0; m < 4; ++m) {
#pragma unroll
                for (int n = 0; n < 4; ++n)
                    Om[pp][lane][(m*4 + n) ^ (lane & 7)] = o[m][n];
                Ml[pp][lane][m]     = mrow[m];
                Ml[pp][lane][4 + m] = lrow[m];
            }
        }
        __syncthreads();
        if (!half) {
#pragma unroll
            for (int m = 0; m < 4; ++m) {
                const float m1 = Ml[pp][lane][m];
                const float l1 = Ml[pp][lane][4 + m];
                const float M  = fmaxf(mrow[m], m1);
                const float f0 = fexp2(mrow[m] - M);
                const float f1 = fexp2(m1 - M);
                const float L  = lrow[m] * f0 + l1 * f1;
                const float inv = 1.0f / L;
                const size_t rowbase = (size_t)(b*SEQL + qb + 16*m + r) * DOUT + h*HDIM;
#pragma unroll
                for (int n = 0; n < 4; ++n) {
                    const f32x4 o1 = Om[pp][lane][(m*4 + n) ^ (lane & 7)];
                    uint2 ov;
                    ov.x = cvtpk((o[m][n][0]*f0 + o1[0]*f1) * inv,
                                 (o[m][n][1]*f0 + o1[1]*f1) * inv);
                    ov.y = cvtpk((o[m][n][2]*f0 + o1[2]*f1) * inv,
                                 (o[m][n][3]*f0 + o1[3]*f1) * inv);
                    *reinterpret_cast<uint2*>(&ctx[rowbase + 16*n + 4*g]) = ov;
                }
            }
        }
        __syncthreads();   // protect Om/Ml reuse in next ti
    }
}

extern "C" void kernel_launch(void* const* d_in, const int* in_sizes, int n_in,
                              void* d_out, int out_size, void* d_ws, size_t ws_size,
                              hipStream_t stream) {
    const float* x  = (const float*)d_in[0];
    const float* Wq = (const float*)d_in[1];
    const float* bq = (const float*)d_in[2];
    const float* Wk = (const float*)d_in[3];
    const float* bk = (const float*)d_in[4];
    const float* Wv = (const float*)d_in[5];
    const float* bv = (const float*)d_in[6];
    const float* Wo = (const float*)d_in[7];
    const float* bo = (const float*)d_in[8];
    float* out = (float*)d_out;
    (void)in_sizes; (void)n_in; (void)out_size; (void)ws_size;

    char* ws = (char*)d_ws;
    __hip_bfloat16* xb  = (__hip_bfloat16*)ws;                       // 16 MB
    __hip_bfloat16* Wt3 = (__hip_bfloat16*)(ws + (16u << 20));       // 6 MB (Q,K,V slabs)
    __hip_bfloat16* Wot = (__hip_bfloat16*)(ws + (22u << 20));       // 2 MB
    __hip_bfloat16* Qb  = (__hip_bfloat16*)(ws + (24u << 20));       // 16 MB
    __hip_bfloat16* Kb  = Qb + (size_t)MTOT * DOUT;                  // 16 MB
    __hip_bfloat16* Vtb = Kb + (size_t)MTOT * DOUT;                  // 16 MB
    __hip_bfloat16* ctx = xb;  // alias: xb dead after the QKV GEMMs

    cvt_bf16<<<2048, 256, 0, stream>>>((const float4*)x, (ushort4*)xb, MTOT * DIN / 4);

    dim3 tb(32, 8);
    transpose_cvt3<<<dim3(32, 32, 3), tb, 0, stream>>>(Wq, Wk, Wv, Wt3);
    transpose_cvt <<<dim3(32, 32),    tb, 0, stream>>>(Wo, Wot);

    // QK fused GEMM (N=2048, swapped orientation). Q scale folds 1/8 * log2(e).
    dim3 gqk(2*DOUT / 128, MTOT / 128);  // (16, 64)
    gemm_mfma<0><<<gqk, 256, 0, stream>>>(xb, Wt3, bq, bk, Qb, Kb,
                                          0.125f * 1.44269504088896f);
    // V GEMM (N=1024, normal orientation) -> V^T
    dim3 gv(DOUT / 128, MTOT / 128);     // (8, 64)
    gemm_mfma<1><<<gv, 256, 0, stream>>>(xb, Wt3 + (size_t)2*DOUT*DIN, bv, nullptr,
                                         Vtb, nullptr, 1.0f);

    // attn: 64 rows/wave, split-K; grid (bh, pair-group) for XCD L2 locality
    dim3 ag(BSZ * NHEAD, 8);  // (64, 8) = 512 blocks x 4 waves
    attn_fwd<<<ag, 256, 0, stream>>>(Qb, Kb, Vtb, ctx);

    // out-proj (swapped orientation, f32x4 stores)
    gemm_mfma<2><<<gv, 256, 0, stream>>>(ctx, Wot, bo, nullptr,
                                         out, nullptr, 1.0f);
}

// Round 20
// 271.674 us; speedup vs baseline: 1.0010x; 1.0010x over previous
//
#include <hip/hip_runtime.h>
#include <hip/hip_bf16.h>
#include <stdint.h>

#define DIN   1024
#define DOUT  1024
#define NHEAD 16
#define HDIM  64
#define SEQL  2048
#define BSZ   4
#define MTOT  (BSZ*SEQL)   // 8192
#define KDIM  1024

typedef __bf16 bf16x8 __attribute__((ext_vector_type(8)));
typedef float  f32x4  __attribute__((ext_vector_type(4)));

__device__ __forceinline__ f32x4 mfma16(bf16x8 a, bf16x8 b, f32x4 c) {
    return __builtin_amdgcn_mfma_f32_16x16x32_bf16(a, b, c, 0, 0, 0);
}

__device__ __forceinline__ void gl_lds16(const void* gsrc, void* ldst) {
    __builtin_amdgcn_global_load_lds(
        (const __attribute__((address_space(1))) uint32_t*)gsrc,
        (__attribute__((address_space(3))) uint32_t*)ldst, 16, 0, 0);
}

// hardware exp2: single v_exp_f32 (attn only)
#if __has_builtin(__builtin_amdgcn_exp2f)
__device__ __forceinline__ float fexp2(float x) { return __builtin_amdgcn_exp2f(x); }
#else
__device__ __forceinline__ float fexp2(float x) { return exp2f(x); }
#endif

// pack 2 f32 -> bf16x2 (attn only)
__device__ __forceinline__ unsigned int cvtpk(float lo, float hi) {
    unsigned int r;
    asm("v_cvt_pk_bf16_f32 %0, %1, %2" : "=v"(r) : "v"(lo), "v"(hi));
    return r;
}

__device__ __forceinline__ unsigned short f2bf(float f) {
    union { __hip_bfloat16 h; unsigned short u; } cv;
    cv.h = __float2bfloat16(f);
    return cv.u;
}

// ---------------- fp32 -> bf16 elementwise (vectorized) ----------------
__global__ void cvt_bf16(const float4* __restrict__ in, ushort4* __restrict__ out, int n4) {
    int idx = blockIdx.x * blockDim.x + threadIdx.x;
    int stride = gridDim.x * blockDim.x;
    for (int i = idx; i < n4; i += stride) {
        float4 v = in[i];
        ushort4 o;
        o.x = f2bf(v.x); o.y = f2bf(v.y); o.z = f2bf(v.z); o.w = f2bf(v.w);
        out[i] = o;
    }
}

// ---- transpose + convert 3x W[1024][1024] f32 -> one Wt3[3072][1024] bf16 ----
__global__ void transpose_cvt3(const float* __restrict__ W0, const float* __restrict__ W1,
                               const float* __restrict__ W2, __hip_bfloat16* __restrict__ Wt3) {
    __shared__ __hip_bfloat16 t[32][33];
    const int tx = threadIdx.x, ty = threadIdx.y;   // (32, 8)
    const int bx = blockIdx.x, by = blockIdx.y, z = blockIdx.z;
    const float* W = (z == 0) ? W0 : (z == 1) ? W1 : W2;
    __hip_bfloat16* Wt = Wt3 + (size_t)z * DOUT * DIN;
#pragma unroll
    for (int r = 0; r < 4; ++r)
        t[ty + 8*r][tx] = __float2bfloat16(W[(size_t)(by*32 + ty + 8*r) * DOUT + bx*32 + tx]);
    __syncthreads();
#pragma unroll
    for (int r = 0; r < 4; ++r)
        Wt[(size_t)(bx*32 + ty + 8*r) * DIN + by*32 + tx] = t[tx][ty + 8*r];
}

__global__ void transpose_cvt(const float* __restrict__ W, __hip_bfloat16* __restrict__ Wt) {
    __shared__ __hip_bfloat16 t[32][33];
    const int tx = threadIdx.x, ty = threadIdx.y;
    const int bx = blockIdx.x, by = blockIdx.y;
#pragma unroll
    for (int r = 0; r < 4; ++r)
        t[ty + 8*r][tx] = __float2bfloat16(W[(size_t)(by*32 + ty + 8*r) * DOUT + bx*32 + tx]);
    __syncthreads();
#pragma unroll
    for (int r = 0; r < 4; ++r)
        Wt[(size_t)(bx*32 + ty + 8*r) * DIN + by*32 + tx] = t[tx][ty + 8*r];
}

// ---------------- 128x128-tile MFMA GEMM (256 threads, 4 waves, BK=32; R11/R16 form) ----------------
template <int EPI>
__global__ __launch_bounds__(256)
void gemm_mfma(const __hip_bfloat16* __restrict__ A,
               const __hip_bfloat16* __restrict__ Bt,
               const float* __restrict__ b0, const float* __restrict__ b1,
               void* __restrict__ o0, void* __restrict__ o1,
               float scale)
{
    __shared__ alignas(16) __hip_bfloat16 As[2][4][128][8];
    __shared__ alignas(16) __hip_bfloat16 Bs[2][4][128][8];

    const int tid  = threadIdx.x;
    const int w    = tid >> 6;
    const int lane = tid & 63;
    const int g    = lane >> 4;
    const int r    = lane & 15;
    const int wr   = w >> 1, wc = w & 1;

    const int row0 = blockIdx.y * 128;
    const int col0 = blockIdx.x * 128;

    f32x4 acc[4][4];
#pragma unroll
    for (int m = 0; m < 4; ++m)
#pragma unroll
        for (int n = 0; n < 4; ++n) acc[m][n] = (f32x4)0.0f;

    auto stage = [&](int buf, int kt) {
        const __hip_bfloat16* ga = A  + (size_t)(row0 + lane) * KDIM + kt*32 + 8*w;
        const __hip_bfloat16* gb = Bt + (size_t)(col0 + lane) * KDIM + kt*32 + 8*w;
        gl_lds16(ga,            &As[buf][w][0][0]);
        gl_lds16(ga + 64*KDIM,  &As[buf][w][64][0]);
        gl_lds16(gb,            &Bs[buf][w][0][0]);
        gl_lds16(gb + 64*KDIM,  &Bs[buf][w][64][0]);
    };

    stage(0, 0);
    __syncthreads();

    const int NKT = KDIM / 32;
    for (int kt = 0; kt < NKT; ++kt) {
        const int cur = kt & 1;
        if (kt + 1 < NKT) stage(cur ^ 1, kt + 1);

        bf16x8 af[4], bfr[4];
#pragma unroll
        for (int m = 0; m < 4; ++m)
            af[m] = *reinterpret_cast<const bf16x8*>(&As[cur][g][64*wr + 16*m + r][0]);
#pragma unroll
        for (int n = 0; n < 4; ++n)
            bfr[n] = *reinterpret_cast<const bf16x8*>(&Bs[cur][g][64*wc + 16*n + r][0]);

#pragma unroll
        for (int m = 0; m < 4; ++m)
#pragma unroll
            for (int n = 0; n < 4; ++n) {
                if (EPI == 1) acc[m][n] = mfma16(af[m], bfr[n], acc[m][n]);  // C
                else          acc[m][n] = mfma16(bfr[n], af[m], acc[m][n]);  // C^T
            }

        __syncthreads();
    }

    if (EPI == 0) {
        const int slab = col0 >> 10;                    // block-uniform
        const float* bp = (slab == 0) ? b0 : b1;
        __hip_bfloat16* op = (__hip_bfloat16*)((slab == 0) ? o0 : o1);
        const float sc = (slab == 0) ? scale : 1.0f;
#pragma unroll
        for (int m = 0; m < 4; ++m) {
            const int rowg = row0 + 64*wr + 16*m + r;
            const int bb = rowg >> 11, sq = rowg & (SEQL-1);
#pragma unroll
            for (int n = 0; n < 4; ++n) {
                const int c2 = (col0 & 1023) + 64*wc + 16*n + 4*g;
                const int hh = c2 >> 6, dd = c2 & (HDIM-1);
                const float4 bv4 = *reinterpret_cast<const float4*>(&bp[c2]);
                ushort4 ov;
                ov.x = f2bf((acc[m][n][0] + bv4.x) * sc);
                ov.y = f2bf((acc[m][n][1] + bv4.y) * sc);
                ov.z = f2bf((acc[m][n][2] + bv4.z) * sc);
                ov.w = f2bf((acc[m][n][3] + bv4.w) * sc);
                *reinterpret_cast<ushort4*>(
                    &op[(((size_t)(bb*NHEAD + hh) * SEQL + sq) << 6) + dd]) = ov;
            }
        }
    } else if (EPI == 1) {
#pragma unroll
        for (int n = 0; n < 4; ++n) {
            const int colg = col0 + 64*wc + 16*n + r;
            const int hh = colg >> 6, dd = colg & (HDIM-1);
            const float bv_ = b0[colg];
#pragma unroll
            for (int m = 0; m < 4; ++m) {
                const int rowg0 = row0 + 64*wr + 16*m + 4*g;
                const int bb = rowg0 >> 11, sq0 = rowg0 & (SEQL-1);
                ushort4 ov;
                ov.x = f2bf(acc[m][n][0] + bv_);
                ov.y = f2bf(acc[m][n][1] + bv_);
                ov.z = f2bf(acc[m][n][2] + bv_);
                ov.w = f2bf(acc[m][n][3] + bv_);
                *reinterpret_cast<ushort4*>(
                    &((__hip_bfloat16*)o0)[((size_t)(bb*NHEAD + hh) * HDIM + dd) * SEQL + sq0]) = ov;
            }
        }
    } else {
#pragma unroll
        for (int m = 0; m < 4; ++m) {
            const int rowg = row0 + 64*wr + 16*m + r;
#pragma unroll
            for (int n = 0; n < 4; ++n) {
                const int colg0 = col0 + 64*wc + 16*n + 4*g;
                const float4 bv4 = *reinterpret_cast<const float4*>(&b0[colg0]);
                float4 ov;
                ov.x = acc[m][n][0] + bv4.x;
                ov.y = acc[m][n][1] + bv4.y;
                ov.z = acc[m][n][2] + bv4.z;
                ov.w = acc[m][n][3] + bv4.w;
                *reinterpret_cast<float4*>(&((float*)o0)[(size_t)rowg * DOUT + colg0]) = ov;
            }
        }
    }
}

// ---------------- causal flash attention (64 rows/wave, split-K, K-dbuf) ----------------
// Q,K: [B,H,S,64] bf16 (Q pre-scaled by log2e/8).  Vt: [B,H,64,S] bf16.
// ctx: [B,S,H*64] bf16.
// R17 structure (scatter-amortized m=4, split-K halves, XCD grid, pointer-bump,
// deferred softmax, fexp2/cvtpk) + K DOUBLE-BUFFER. Rationale: R17 is at
// 2 waves/SIMD (supply 2048 waves; VGPR 168) -- adding +32 VGPR for the K-dbuf
// keeps 2 waves/SIMD (512/200=2), so the ILP is occupancy-FREE (unlike R15,
// where the same change at m=2 crossed 3->2 waves/SIMD and regressed). Next-step
// K is in flight across this step's softmax+PV (~700 cyc at m=4).
__global__ __launch_bounds__(256)
void attn_fwd(const __hip_bfloat16* __restrict__ Q,
              const __hip_bfloat16* __restrict__ K,
              const __hip_bfloat16* __restrict__ Vt,
              __hip_bfloat16* __restrict__ ctx)
{
    __shared__ alignas(16) __hip_bfloat16 Ps[4][16][64];  // 8KB, per-wave, per-m reuse
    __shared__ alignas(16) f32x4 Om[2][64][16];           // 32KB merge buffer
    __shared__ float Ml[2][64][9];                        // m[4], l[4] (+pad)

    const int tid  = threadIdx.x;
    const int w    = tid >> 6;
    const int lane = tid & 63;
    const int g    = lane >> 4;
    const int r    = lane & 15;
    const int swz  = (r & 7) << 3;   // element-XOR within a 64-elt (128B) row
    const int pp   = w >> 1;         // pair index within block (0..1)
    const int half = w & 1;          // key-range half

    const int bh = blockIdx.x;       // XCD-local: id%8 == bh%8
    const int b  = bh >> 4, h = bh & 15;

    const __hip_bfloat16* Qh = Q  + (size_t)bh * SEQL * HDIM;
    const __hip_bfloat16* Kh = K  + (size_t)bh * SEQL * HDIM;
    const __hip_bfloat16* Vh = Vt + (size_t)bh * HDIM * SEQL;

    const int sp = blockIdx.y * 2 + pp;   // strip-pair id 0..15

#pragma unroll 1
    for (int ti = 0; ti < 2; ++ti) {
        const int strip = ti ? (31 - sp) : sp;
        const int qb = strip * 64;

        bf16x8 qf[4][2];
#pragma unroll
        for (int m = 0; m < 4; ++m)
#pragma unroll
            for (int hh = 0; hh < 2; ++hh)
                qf[m][hh] = *reinterpret_cast<const bf16x8*>(
                    Qh + (size_t)(qb + 16*m + r) * HDIM + 32*hh + 8*g);

        f32x4 o[4][4];
        float mrow[4], lrow[4];
#pragma unroll
        for (int m = 0; m < 4; ++m) {
#pragma unroll
            for (int n = 0; n < 4; ++n) o[m][n] = (f32x4)0.0f;
            mrow[m] = -1e30f; lrow[m] = 0.0f;
        }

        const int nst = strip + 1;
        const int ns2 = (nst + 1) >> 1;
        const int k0  = half ? ns2 : 0;
        const int k1  = half ? nst : ns2;

        // pointer-bump bases: per-lane, step-invariant immediate offsets.
        const __hip_bfloat16* kp01 = Kh + (size_t)(k0*64 + r) * HDIM + 8*g;
        const __hip_bfloat16* kp23 = kp01 + 32*HDIM;
        const __hip_bfloat16* vp0  = Vh + (size_t)r * SEQL + (size_t)k0*64 + 8*g;
        const __hip_bfloat16* vp1  = vp0 + (size_t)16*SEQL;
        const __hip_bfloat16* vp2  = vp0 + (size_t)32*SEQL;
        const __hip_bfloat16* vp3  = vp0 + (size_t)48*SEQL;

        bf16x8 kA[4][2], kB[4][2];

        auto loadK = [&](bf16x8 (&kf)[4][2]) __attribute__((always_inline)) {
#pragma unroll
            for (int hh = 0; hh < 2; ++hh) {
                kf[0][hh] = *reinterpret_cast<const bf16x8*>(kp01 + hh*32);
                kf[1][hh] = *reinterpret_cast<const bf16x8*>(kp01 + 16*HDIM + hh*32);
                kf[2][hh] = *reinterpret_cast<const bf16x8*>(kp23 + hh*32);
                kf[3][hh] = *reinterpret_cast<const bf16x8*>(kp23 + 16*HDIM + hh*32);
            }
            kp01 += 64*HDIM; kp23 += 64*HDIM;
        };

        auto step = [&](bf16x8 (&KC)[4][2], bf16x8 (&KN)[4][2], int kt)
                        __attribute__((always_inline)) {
            const int key0 = kt * 64;

            // V for THIS step (consumed after softmax); K for NEXT step (in
            // flight across this whole step's softmax+PV)
            bf16x8 vf[4][2];
#pragma unroll
            for (int hh = 0; hh < 2; ++hh) {
                vf[0][hh] = *reinterpret_cast<const bf16x8*>(vp0 + hh*32);
                vf[1][hh] = *reinterpret_cast<const bf16x8*>(vp1 + hh*32);
                vf[2][hh] = *reinterpret_cast<const bf16x8*>(vp2 + hh*32);
                vf[3][hh] = *reinterpret_cast<const bf16x8*>(vp3 + hh*32);
            }
            vp0 += 64; vp1 += 64; vp2 += 64; vp3 += 64;
            if (kt + 1 < k1) loadK(KN);

            const bool lastkt = (kt == nst - 1);

#pragma unroll
            for (int m = 0; m < 4; ++m) {
                // S^T[key = key0+16c+4g+j][qrow = qb+16m+r]
                f32x4 s[4];
                __builtin_amdgcn_s_setprio(1);
#pragma unroll
                for (int c = 0; c < 4; ++c) {
                    f32x4 t = (f32x4)0.0f;
                    t = mfma16(KC[c][0], qf[m][0], t);
                    t = mfma16(KC[c][1], qf[m][1], t);
                    s[c] = t;
                }
                __builtin_amdgcn_s_setprio(0);

                const int qrow = qb + 16*m + r;
                if (lastkt) {   // causal mask only in the boundary step
#pragma unroll
                    for (int c = 0; c < 4; ++c) {
                        const int kb = key0 + 16*c + 4*g;
#pragma unroll
                        for (int j = 0; j < 4; ++j)
                            if (kb + j > qrow) s[c][j] = -1e30f;
                    }
                }

                // lane-local max over this lane's 16 scores
                float t0 = fmaxf(fmaxf(s[0][0], s[0][1]), fmaxf(s[0][2], s[0][3]));
                float t1 = fmaxf(fmaxf(s[1][0], s[1][1]), fmaxf(s[1][2], s[1][3]));
                float t2 = fmaxf(fmaxf(s[2][0], s[2][1]), fmaxf(s[2][2], s[2][3]));
                float t3 = fmaxf(fmaxf(s[3][0], s[3][1]), fmaxf(s[3][2], s[3][3]));
                float pml = fmaxf(fmaxf(t0, t1), fmaxf(t2, t3));

                // deferred rescale: cross-lane reduce ONLY when triggered
                if (__any(pml > mrow[m] + 11.0f)) {
                    float pm = fmaxf(pml, __shfl_xor(pml, 16));
                    pm = fmaxf(pm, __shfl_xor(pm, 32));
                    const float mnew = fmaxf(mrow[m], pm);
                    const float fac  = fexp2(mrow[m] - mnew);
                    mrow[m] = mnew;
                    lrow[m] *= fac;
#pragma unroll
                    for (int n = 0; n < 4; ++n) o[m][n] *= fac;
                }

                float p[4][4];
#pragma unroll
                for (int c = 0; c < 4; ++c)
#pragma unroll
                    for (int j = 0; j < 4; ++j)
                        p[c][j] = fexp2(s[c][j] - mrow[m]);

                // lane-partial row sum (reduced across g-lanes once per strip)
                float u0 = (p[0][0] + p[0][1]) + (p[0][2] + p[0][3]);
                float u1 = (p[1][0] + p[1][1]) + (p[1][2] + p[1][3]);
                float u2 = (p[2][0] + p[2][1]) + (p[2][2] + p[2][3]);
                float u3 = (p[3][0] + p[3][1]) + (p[3][2] + p[3][3]);
                lrow[m] += (u0 + u1) + (u2 + u3);

                // pack P row-fragment -> swizzled ds_write (Ps reused per m)
#pragma unroll
                for (int c = 0; c < 4; ++c) {
                    uint2 pk;
                    pk.x = cvtpk(p[c][0], p[c][1]);
                    pk.y = cvtpk(p[c][2], p[c][3]);
                    *reinterpret_cast<uint2*>(&Ps[w][r][(16*c + 4*g) ^ swz]) = pk;
                }

                // P fragments (swizzled b128 reads) + PV as mfma(V^T, P^T)
                bf16x8 pf[2];
#pragma unroll
                for (int hh = 0; hh < 2; ++hh)
                    pf[hh] = *reinterpret_cast<const bf16x8*>(
                        &Ps[w][r][(32*hh + 8*g) ^ swz]);

                __builtin_amdgcn_s_setprio(1);
#pragma unroll
                for (int n = 0; n < 4; ++n) {
                    o[m][n] = mfma16(vf[n][0], pf[0], o[m][n]);
                    o[m][n] = mfma16(vf[n][1], pf[1], o[m][n]);
                }
                __builtin_amdgcn_s_setprio(0);
            }
        };

        loadK(kA);
        int kt = k0;
        while (kt < k1) {
            step(kA, kB, kt); if (++kt >= k1) break;
            step(kB, kA, kt); ++kt;
        }

        // reduce lane-partial lrow across the 4 g-lanes (once per strip)
#pragma unroll
        for (int m = 0; m < 4; ++m) {
            lrow[m] += __shfl_xor(lrow[m], 16);
            lrow[m] += __shfl_xor(lrow[m], 32);
        }

        // ----- split-K merge: half1 publishes partials, half0 merges + stores -----
        if (half) {
#pragma unroll
            for (int m = 0; m < 4; ++m) {
#pragma unroll
                for (int n = 0; n < 4; ++n)
                    Om[pp][lane][(m*4 + n) ^ (lane & 7)] = o[m][n];
                Ml[pp][lane][m]     = mrow[m];
                Ml[pp][lane][4 + m] = lrow[m];
            }
        }
        __syncthreads();
        if (!half) {
#pragma unroll
            for (int m = 0; m < 4; ++m) {
                const float m1 = Ml[pp][lane][m];
                const float l1 = Ml[pp][lane][4 + m];
                const float M  = fmaxf(mrow[m], m1);
                const float f0 = fexp2(mrow[m] - M);
                const float f1 = fexp2(m1 - M);
                const float L  = lrow[m] * f0 + l1 * f1;
                const float inv = 1.0f / L;
                const size_t rowbase = (size_t)(b*SEQL + qb + 16*m + r) * DOUT + h*HDIM;
#pragma unroll
                for (int n = 0; n < 4; ++n) {
                    const f32x4 o1 = Om[pp][lane][(m*4 + n) ^ (lane & 7)];
                    uint2 ov;
                    ov.x = cvtpk((o[m][n][0]*f0 + o1[0]*f1) * inv,
                                 (o[m][n][1]*f0 + o1[1]*f1) * inv);
                    ov.y = cvtpk((o[m][n][2]*f0 + o1[2]*f1) * inv,
                                 (o[m][n][3]*f0 + o1[3]*f1) * inv);
                    *reinterpret_cast<uint2*>(&ctx[rowbase + 16*n + 4*g]) = ov;
                }
            }
        }
        __syncthreads();   // protect Om/Ml reuse in next ti
    }
}

extern "C" void kernel_launch(void* const* d_in, const int* in_sizes, int n_in,
                              void* d_out, int out_size, void* d_ws, size_t ws_size,
                              hipStream_t stream) {
    const float* x  = (const float*)d_in[0];
    const float* Wq = (const float*)d_in[1];
    const float* bq = (const float*)d_in[2];
    const float* Wk = (const float*)d_in[3];
    const float* bk = (const float*)d_in[4];
    const float* Wv = (const float*)d_in[5];
    const float* bv = (const float*)d_in[6];
    const float* Wo = (const float*)d_in[7];
    const float* bo = (const float*)d_in[8];
    float* out = (float*)d_out;
    (void)in_sizes; (void)n_in; (void)out_size; (void)ws_size;

    char* ws = (char*)d_ws;
    __hip_bfloat16* xb  = (__hip_bfloat16*)ws;                       // 16 MB
    __hip_bfloat16* Wt3 = (__hip_bfloat16*)(ws + (16u << 20));       // 6 MB (Q,K,V slabs)
    __hip_bfloat16* Wot = (__hip_bfloat16*)(ws + (22u << 20));       // 2 MB
    __hip_bfloat16* Qb  = (__hip_bfloat16*)(ws + (24u << 20));       // 16 MB
    __hip_bfloat16* Kb  = Qb + (size_t)MTOT * DOUT;                  // 16 MB
    __hip_bfloat16* Vtb = Kb + (size_t)MTOT * DOUT;                  // 16 MB
    __hip_bfloat16* ctx = xb;  // alias: xb dead after the QKV GEMMs

    cvt_bf16<<<2048, 256, 0, stream>>>((const float4*)x, (ushort4*)xb, MTOT * DIN / 4);

    dim3 tb(32, 8);
    transpose_cvt3<<<dim3(32, 32, 3), tb, 0, stream>>>(Wq, Wk, Wv, Wt3);
    transpose_cvt <<<dim3(32, 32),    tb, 0, stream>>>(Wo, Wot);

    // QK fused GEMM (N=2048, swapped orientation). Q scale folds 1/8 * log2(e).
    dim3 gqk(2*DOUT / 128, MTOT / 128);  // (16, 64)
    gemm_mfma<0><<<gqk, 256, 0, stream>>>(xb, Wt3, bq, bk, Qb, Kb,
                                          0.125f * 1.44269504088896f);
    // V GEMM (N=1024, normal orientation) -> V^T
    dim3 gv(DOUT / 128, MTOT / 128);     // (8, 64)
    gemm_mfma<1><<<gv, 256, 0, stream>>>(xb, Wt3 + (size_t)2*DOUT*DIN, bv, nullptr,
                                         Vtb, nullptr, 1.0f);

    // attn: 64 rows/wave, split-K; grid (bh, pair-group) for XCD L2 locality
    dim3 ag(BSZ * NHEAD, 8);  // (64, 8) = 512 blocks x 4 waves
    attn_fwd<<<ag, 256, 0, stream>>>(Qb, Kb, Vtb, ctx);

    // out-proj (swapped orientation, f32x4 stores)
    gemm_mfma<2><<<gv, 256, 0, stream>>>(ctx, Wot, bo, nullptr,
                                         out, nullptr, 1.0f);
}

// Round 22
// 259.966 us; speedup vs baseline: 1.0461x; 1.0450x over previous
//
#include <hip/hip_runtime.h>
#include <hip/hip_bf16.h>
#include <stdint.h>

#define DIN   1024
#define DOUT  1024
#define NHEAD 16
#define HDIM  64
#define SEQL  2048
#define BSZ   4
#define MTOT  (BSZ*SEQL)   // 8192
#define KDIM  1024

typedef __bf16 bf16x8 __attribute__((ext_vector_type(8)));
typedef float  f32x4  __attribute__((ext_vector_type(4)));

__device__ __forceinline__ f32x4 mfma16(bf16x8 a, bf16x8 b, f32x4 c) {
    return __builtin_amdgcn_mfma_f32_16x16x32_bf16(a, b, c, 0, 0, 0);
}

__device__ __forceinline__ void gl_lds16(const void* gsrc, void* ldst) {
    __builtin_amdgcn_global_load_lds(
        (const __attribute__((address_space(1))) uint32_t*)gsrc,
        (__attribute__((address_space(3))) uint32_t*)ldst, 16, 0, 0);
}

// hardware exp2: single v_exp_f32 (attn only)
#if __has_builtin(__builtin_amdgcn_exp2f)
__device__ __forceinline__ float fexp2(float x) { return __builtin_amdgcn_exp2f(x); }
#else
__device__ __forceinline__ float fexp2(float x) { return exp2f(x); }
#endif

// pack 2 f32 -> bf16x2 (attn only)
__device__ __forceinline__ unsigned int cvtpk(float lo, float hi) {
    unsigned int r;
    asm("v_cvt_pk_bf16_f32 %0, %1, %2" : "=v"(r) : "v"(lo), "v"(hi));
    return r;
}

__device__ __forceinline__ unsigned short f2bf(float f) {
    union { __hip_bfloat16 h; unsigned short u; } cv;
    cv.h = __float2bfloat16(f);
    return cv.u;
}

// ---------------- fp32 -> bf16 elementwise (vectorized) ----------------
__global__ void cvt_bf16(const float4* __restrict__ in, ushort4* __restrict__ out, int n4) {
    int idx = blockIdx.x * blockDim.x + threadIdx.x;
    int stride = gridDim.x * blockDim.x;
    for (int i = idx; i < n4; i += stride) {
        float4 v = in[i];
        ushort4 o;
        o.x = f2bf(v.x); o.y = f2bf(v.y); o.z = f2bf(v.z); o.w = f2bf(v.w);
        out[i] = o;
    }
}

// ---- transpose + convert 3x W[1024][1024] f32 -> one Wt3[3072][1024] bf16 ----
__global__ void transpose_cvt3(const float* __restrict__ W0, const float* __restrict__ W1,
                               const float* __restrict__ W2, __hip_bfloat16* __restrict__ Wt3) {
    __shared__ __hip_bfloat16 t[32][33];
    const int tx = threadIdx.x, ty = threadIdx.y;   // (32, 8)
    const int bx = blockIdx.x, by = blockIdx.y, z = blockIdx.z;
    const float* W = (z == 0) ? W0 : (z == 1) ? W1 : W2;
    __hip_bfloat16* Wt = Wt3 + (size_t)z * DOUT * DIN;
#pragma unroll
    for (int r = 0; r < 4; ++r)
        t[ty + 8*r][tx] = __float2bfloat16(W[(size_t)(by*32 + ty + 8*r) * DOUT + bx*32 + tx]);
    __syncthreads();
#pragma unroll
    for (int r = 0; r < 4; ++r)
        Wt[(size_t)(bx*32 + ty + 8*r) * DIN + by*32 + tx] = t[tx][ty + 8*r];
}

__global__ void transpose_cvt(const float* __restrict__ W, __hip_bfloat16* __restrict__ Wt) {
    __shared__ __hip_bfloat16 t[32][33];
    const int tx = threadIdx.x, ty = threadIdx.y;
    const int bx = blockIdx.x, by = blockIdx.y;
#pragma unroll
    for (int r = 0; r < 4; ++r)
        t[ty + 8*r][tx] = __float2bfloat16(W[(size_t)(by*32 + ty + 8*r) * DOUT + bx*32 + tx]);
    __syncthreads();
#pragma unroll
    for (int r = 0; r < 4; ++r)
        Wt[(size_t)(bx*32 + ty + 8*r) * DIN + by*32 + tx] = t[tx][ty + 8*r];
}

// ---------------- 128x128-tile MFMA GEMM (256 threads, 4 waves, BK=32) ----------------
// EPI 0 (QK, swapped mfma -> C^T fragments, packed 8B stores)
// EPI 1 (V, normal mfma -> FRAGMENT-PACKED V: per (bh, 64-key block kb) 4096
//        elems at (((kb*4+n)*2+hh)*64 + lane)*8 + e, so attn's V loads are
//        coalesced lane-linear reads instead of 16x 4KB-strided requests)
// EPI 2 (out-proj, swapped mfma, packed 16B f32 stores)
template <int EPI>
__global__ __launch_bounds__(256)
void gemm_mfma(const __hip_bfloat16* __restrict__ A,
               const __hip_bfloat16* __restrict__ Bt,
               const float* __restrict__ b0, const float* __restrict__ b1,
               void* __restrict__ o0, void* __restrict__ o1,
               float scale)
{
    __shared__ alignas(16) __hip_bfloat16 As[2][4][128][8];
    __shared__ alignas(16) __hip_bfloat16 Bs[2][4][128][8];

    const int tid  = threadIdx.x;
    const int w    = tid >> 6;
    const int lane = tid & 63;
    const int g    = lane >> 4;
    const int r    = lane & 15;
    const int wr   = w >> 1, wc = w & 1;

    const int row0 = blockIdx.y * 128;
    const int col0 = blockIdx.x * 128;

    f32x4 acc[4][4];
#pragma unroll
    for (int m = 0; m < 4; ++m)
#pragma unroll
        for (int n = 0; n < 4; ++n) acc[m][n] = (f32x4)0.0f;

    auto stage = [&](int buf, int kt) {
        const __hip_bfloat16* ga = A  + (size_t)(row0 + lane) * KDIM + kt*32 + 8*w;
        const __hip_bfloat16* gb = Bt + (size_t)(col0 + lane) * KDIM + kt*32 + 8*w;
        gl_lds16(ga,            &As[buf][w][0][0]);
        gl_lds16(ga + 64*KDIM,  &As[buf][w][64][0]);
        gl_lds16(gb,            &Bs[buf][w][0][0]);
        gl_lds16(gb + 64*KDIM,  &Bs[buf][w][64][0]);
    };

    stage(0, 0);
    __syncthreads();

    const int NKT = KDIM / 32;
    for (int kt = 0; kt < NKT; ++kt) {
        const int cur = kt & 1;
        if (kt + 1 < NKT) stage(cur ^ 1, kt + 1);

        bf16x8 af[4], bfr[4];
#pragma unroll
        for (int m = 0; m < 4; ++m)
            af[m] = *reinterpret_cast<const bf16x8*>(&As[cur][g][64*wr + 16*m + r][0]);
#pragma unroll
        for (int n = 0; n < 4; ++n)
            bfr[n] = *reinterpret_cast<const bf16x8*>(&Bs[cur][g][64*wc + 16*n + r][0]);

#pragma unroll
        for (int m = 0; m < 4; ++m)
#pragma unroll
            for (int n = 0; n < 4; ++n) {
                if (EPI == 1) acc[m][n] = mfma16(af[m], bfr[n], acc[m][n]);  // C
                else          acc[m][n] = mfma16(bfr[n], af[m], acc[m][n]);  // C^T
            }

        __syncthreads();
    }

    if (EPI == 0) {
        const int slab = col0 >> 10;                    // block-uniform
        const float* bp = (slab == 0) ? b0 : b1;
        __hip_bfloat16* op = (__hip_bfloat16*)((slab == 0) ? o0 : o1);
        const float sc = (slab == 0) ? scale : 1.0f;
#pragma unroll
        for (int m = 0; m < 4; ++m) {
            const int rowg = row0 + 64*wr + 16*m + r;
            const int bb = rowg >> 11, sq = rowg & (SEQL-1);
#pragma unroll
            for (int n = 0; n < 4; ++n) {
                const int c2 = (col0 & 1023) + 64*wc + 16*n + 4*g;
                const int hh = c2 >> 6, dd = c2 & (HDIM-1);
                const float4 bv4 = *reinterpret_cast<const float4*>(&bp[c2]);
                ushort4 ov;
                ov.x = f2bf((acc[m][n][0] + bv4.x) * sc);
                ov.y = f2bf((acc[m][n][1] + bv4.y) * sc);
                ov.z = f2bf((acc[m][n][2] + bv4.z) * sc);
                ov.w = f2bf((acc[m][n][3] + bv4.w) * sc);
                *reinterpret_cast<ushort4*>(
                    &op[(((size_t)(bb*NHEAD + hh) * SEQL + sq) << 6) + dd]) = ov;
            }
        }
    } else if (EPI == 1) {
        // fragment-packed V: element V[s][d] -> Vff at
        //   bh = b*16 + d-head; kb = s/64; hh = (s%64)/32; g' = (s%32)/8; e = s%8
        //   n' = (d%64)/16; r' = d%16
        //   offset = bh*S*64 + (((kb*4 + n')*2 + hh)*64 + 16*g' + r')*8 + e
        // (kb-block = 4096 elems; n-stride 1024, hh-stride 512, lane-linear *8)
        // Each (m,n) writes 4 consecutive s (e0..e0+3, e0 in {0,4}) -> one 8B store.
#pragma unroll
        for (int n = 0; n < 4; ++n) {
            const int colg = col0 + 64*wc + 16*n + r;
            const int hhd = colg >> 6, dd = colg & (HDIM-1);
            const int n2 = dd >> 4, r2 = dd & 15;
            const float bv_ = b0[colg];
#pragma unroll
            for (int m = 0; m < 4; ++m) {
                const int rowg0 = row0 + 64*wr + 16*m + 4*g;
                const int bb = rowg0 >> 11, sq0 = rowg0 & (SEQL-1);
                const int kb = sq0 >> 6;
                const int hh2 = (sq0 >> 5) & 1;
                const int g2 = (sq0 >> 3) & 3;
                const int e0 = sq0 & 7;   // 0 or 4
                ushort4 ov;
                ov.x = f2bf(acc[m][n][0] + bv_);
                ov.y = f2bf(acc[m][n][1] + bv_);
                ov.z = f2bf(acc[m][n][2] + bv_);
                ov.w = f2bf(acc[m][n][3] + bv_);
                const size_t off = (size_t)(bb*NHEAD + hhd) * (SEQL*HDIM)
                    + ((((size_t)kb*4 + n2)*2 + hh2)*64 + 16*g2 + r2)*8 + e0;
                *reinterpret_cast<ushort4*>(&((__hip_bfloat16*)o0)[off]) = ov;
            }
        }
    } else {
#pragma unroll
        for (int m = 0; m < 4; ++m) {
            const int rowg = row0 + 64*wr + 16*m + r;
#pragma unroll
            for (int n = 0; n < 4; ++n) {
                const int colg0 = col0 + 64*wc + 16*n + 4*g;
                const float4 bv4 = *reinterpret_cast<const float4*>(&b0[colg0]);
                float4 ov;
                ov.x = acc[m][n][0] + bv4.x;
                ov.y = acc[m][n][1] + bv4.y;
                ov.z = acc[m][n][2] + bv4.z;
                ov.w = acc[m][n][3] + bv4.w;
                *reinterpret_cast<float4*>(&((float*)o0)[(size_t)rowg * DOUT + colg0]) = ov;
            }
        }
    }
}

// ---------------- causal flash attention (R17 body + fragment-packed V) ----------------
// Q,K: [B,H,S,64] bf16 (Q pre-scaled by log2e/8).
// Vff: fragment-packed (see EPI1).  ctx: [B,S,H*64] bf16.
// R17 structure exactly (64 rows/wave m=4, split-K halves, XCD grid, pointer-bump,
// deferred softmax, fexp2/cvtpk; NO K-prefetch -- R9/R15/R20 all regressed).
// V loads are coalesced lane-linear reads: addr = Vff + kt*4096 + n*1024 +
// hh*512 + lane*8  (R21 BUG: used kt*8192 and n2-offset 4096 -- reader did not
// match the writer's 4096-elem kb-block; fixed here).
__global__ __launch_bounds__(256)
void attn_fwd(const __hip_bfloat16* __restrict__ Q,
              const __hip_bfloat16* __restrict__ K,
              const __hip_bfloat16* __restrict__ Vff,
              __hip_bfloat16* __restrict__ ctx)
{
    __shared__ alignas(16) __hip_bfloat16 Ps[4][16][64];  // 8KB, per-wave, per-m reuse
    __shared__ alignas(16) f32x4 Om[2][64][16];           // 32KB merge buffer
    __shared__ float Ml[2][64][9];                        // m[4], l[4] (+pad)

    const int tid  = threadIdx.x;
    const int w    = tid >> 6;
    const int lane = tid & 63;
    const int g    = lane >> 4;
    const int r    = lane & 15;
    const int swz  = (r & 7) << 3;   // element-XOR within a 64-elt (128B) row
    const int pp   = w >> 1;         // pair index within block (0..1)
    const int half = w & 1;          // key-range half

    const int bh = blockIdx.x;       // XCD-local: id%8 == bh%8
    const int b  = bh >> 4, h = bh & 15;

    const __hip_bfloat16* Qh = Q   + (size_t)bh * SEQL * HDIM;
    const __hip_bfloat16* Kh = K   + (size_t)bh * SEQL * HDIM;
    const __hip_bfloat16* Vh = Vff + (size_t)bh * SEQL * HDIM;

    const int sp = blockIdx.y * 2 + pp;   // strip-pair id 0..15

#pragma unroll 1
    for (int ti = 0; ti < 2; ++ti) {
        const int strip = ti ? (31 - sp) : sp;
        const int qb = strip * 64;

        bf16x8 qf[4][2];
#pragma unroll
        for (int m = 0; m < 4; ++m)
#pragma unroll
            for (int hh = 0; hh < 2; ++hh)
                qf[m][hh] = *reinterpret_cast<const bf16x8*>(
                    Qh + (size_t)(qb + 16*m + r) * HDIM + 32*hh + 8*g);

        f32x4 o[4][4];
        float mrow[4], lrow[4];
#pragma unroll
        for (int m = 0; m < 4; ++m) {
#pragma unroll
            for (int n = 0; n < 4; ++n) o[m][n] = (f32x4)0.0f;
            mrow[m] = -1e30f; lrow[m] = 0.0f;
        }

        const int nst = strip + 1;
        const int ns2 = (nst + 1) >> 1;
        const int k0  = half ? ns2 : 0;
        const int k1  = half ? nst : ns2;

        // pointer-bump bases: per-lane, step-invariant immediate offsets.
        const __hip_bfloat16* kp01 = Kh + (size_t)(k0*64 + r) * HDIM + 8*g;
        const __hip_bfloat16* kp23 = kp01 + 32*HDIM;
        // fragment-packed V: kb-block = 4096 elems; lane-linear. vpA: n=0,1; vpB: n=2,3.
        const __hip_bfloat16* vpA = Vh + (size_t)k0 * 4096 + lane * 8;
        const __hip_bfloat16* vpB = vpA + 2048;

#pragma unroll 1
        for (int kt = k0; kt < k1; ++kt) {
            const int key0 = kt * 64;

            // K (as before) + V (coalesced lane-linear reads) for THIS step
            bf16x8 kf[4][2], vf[4][2];
#pragma unroll
            for (int hh = 0; hh < 2; ++hh) {
                kf[0][hh] = *reinterpret_cast<const bf16x8*>(kp01 + hh*32);
                kf[1][hh] = *reinterpret_cast<const bf16x8*>(kp01 + 16*HDIM + hh*32);
                kf[2][hh] = *reinterpret_cast<const bf16x8*>(kp23 + hh*32);
                kf[3][hh] = *reinterpret_cast<const bf16x8*>(kp23 + 16*HDIM + hh*32);
                vf[0][hh] = *reinterpret_cast<const bf16x8*>(vpA + hh*512);
                vf[1][hh] = *reinterpret_cast<const bf16x8*>(vpA + 1024 + hh*512);
                vf[2][hh] = *reinterpret_cast<const bf16x8*>(vpB + hh*512);
                vf[3][hh] = *reinterpret_cast<const bf16x8*>(vpB + 1024 + hh*512);
            }
            kp01 += 64*HDIM; kp23 += 64*HDIM;
            vpA += 4096; vpB += 4096;

            const bool lastkt = (kt == nst - 1);

#pragma unroll
            for (int m = 0; m < 4; ++m) {
                // S^T[key = key0+16c+4g+j][qrow = qb+16m+r]
                f32x4 s[4];
                __builtin_amdgcn_s_setprio(1);
#pragma unroll
                for (int c = 0; c < 4; ++c) {
                    f32x4 t = (f32x4)0.0f;
                    t = mfma16(kf[c][0], qf[m][0], t);
                    t = mfma16(kf[c][1], qf[m][1], t);
                    s[c] = t;
                }
                __builtin_amdgcn_s_setprio(0);

                const int qrow = qb + 16*m + r;
                if (lastkt) {   // causal mask only in the boundary step
#pragma unroll
                    for (int c = 0; c < 4; ++c) {
                        const int kb = key0 + 16*c + 4*g;
#pragma unroll
                        for (int j = 0; j < 4; ++j)
                            if (kb + j > qrow) s[c][j] = -1e30f;
                    }
                }

                // lane-local max over this lane's 16 scores
                float t0 = fmaxf(fmaxf(s[0][0], s[0][1]), fmaxf(s[0][2], s[0][3]));
                float t1 = fmaxf(fmaxf(s[1][0], s[1][1]), fmaxf(s[1][2], s[1][3]));
                float t2 = fmaxf(fmaxf(s[2][0], s[2][1]), fmaxf(s[2][2], s[2][3]));
                float t3 = fmaxf(fmaxf(s[3][0], s[3][1]), fmaxf(s[3][2], s[3][3]));
                float pml = fmaxf(fmaxf(t0, t1), fmaxf(t2, t3));

                // deferred rescale: cross-lane reduce ONLY when triggered
                if (__any(pml > mrow[m] + 11.0f)) {
                    float pm = fmaxf(pml, __shfl_xor(pml, 16));
                    pm = fmaxf(pm, __shfl_xor(pm, 32));
                    const float mnew = fmaxf(mrow[m], pm);
                    const float fac  = fexp2(mrow[m] - mnew);
                    mrow[m] = mnew;
                    lrow[m] *= fac;
#pragma unroll
                    for (int n = 0; n < 4; ++n) o[m][n] *= fac;
                }

                float p[4][4];
#pragma unroll
                for (int c = 0; c < 4; ++c)
#pragma unroll
                    for (int j = 0; j < 4; ++j)
                        p[c][j] = fexp2(s[c][j] - mrow[m]);

                // lane-partial row sum (reduced across g-lanes once per strip)
                float u0 = (p[0][0] + p[0][1]) + (p[0][2] + p[0][3]);
                float u1 = (p[1][0] + p[1][1]) + (p[1][2] + p[1][3]);
                float u2 = (p[2][0] + p[2][1]) + (p[2][2] + p[2][3]);
                float u3 = (p[3][0] + p[3][1]) + (p[3][2] + p[3][3]);
                lrow[m] += (u0 + u1) + (u2 + u3);

                // pack P row-fragment -> swizzled ds_write (Ps reused per m)
#pragma unroll
                for (int c = 0; c < 4; ++c) {
                    uint2 pk;
                    pk.x = cvtpk(p[c][0], p[c][1]);
                    pk.y = cvtpk(p[c][2], p[c][3]);
                    *reinterpret_cast<uint2*>(&Ps[w][r][(16*c + 4*g) ^ swz]) = pk;
                }

                // P fragments (swizzled b128 reads) + PV as mfma(V^T, P^T)
                bf16x8 pf[2];
#pragma unroll
                for (int hh = 0; hh < 2; ++hh)
                    pf[hh] = *reinterpret_cast<const bf16x8*>(
                        &Ps[w][r][(32*hh + 8*g) ^ swz]);

                __builtin_amdgcn_s_setprio(1);
#pragma unroll
                for (int n = 0; n < 4; ++n) {
                    o[m][n] = mfma16(vf[n][0], pf[0], o[m][n]);
                    o[m][n] = mfma16(vf[n][1], pf[1], o[m][n]);
                }
                __builtin_amdgcn_s_setprio(0);
            }
        }

        // reduce lane-partial lrow across the 4 g-lanes (once per strip)
#pragma unroll
        for (int m = 0; m < 4; ++m) {
            lrow[m] += __shfl_xor(lrow[m], 16);
            lrow[m] += __shfl_xor(lrow[m], 32);
        }

        // ----- split-K merge: half1 publishes partials, half0 merges + stores -----
        if (half) {
#pragma unroll
            for (int m = 0; m < 4; ++m) {
#pragma unroll
                for (int n = 0; n < 4; ++n)
                    Om[pp][lane][(m*4 + n) ^ (lane & 7)] = o[m][n];
                Ml[pp][lane][m]     = mrow[m];
                Ml[pp][lane][4 + m] = lrow[m];
            }
        }
        __syncthreads();
        if (!half) {
#pragma unroll
            for (int m = 0; m < 4; ++m) {
                const float m1 = Ml[pp][lane][m];
                const float l1 = Ml[pp][lane][4 + m];
                const float M  = fmaxf(mrow[m], m1);
                const float f0 = fexp2(mrow[m] - M);
                const float f1 = fexp2(m1 - M);
                const float L  = lrow[m] * f0 + l1 * f1;
                const float inv = 1.0f / L;
                const size_t rowbase = (size_t)(b*SEQL + qb + 16*m + r) * DOUT + h*HDIM;
#pragma unroll
                for (int n = 0; n < 4; ++n) {
                    const f32x4 o1 = Om[pp][lane][(m*4 + n) ^ (lane & 7)];
                    uint2 ov;
                    ov.x = cvtpk((o[m][n][0]*f0 + o1[0]*f1) * inv,
                                 (o[m][n][1]*f0 + o1[1]*f1) * inv);
                    ov.y = cvtpk((o[m][n][2]*f0 + o1[2]*f1) * inv,
                                 (o[m][n][3]*f0 + o1[3]*f1) * inv);
                    *reinterpret_cast<uint2*>(&ctx[rowbase + 16*n + 4*g]) = ov;
                }
            }
        }
        __syncthreads();   // protect Om/Ml reuse in next ti
    }
}

extern "C" void kernel_launch(void* const* d_in, const int* in_sizes, int n_in,
                              void* d_out, int out_size, void* d_ws, size_t ws_size,
                              hipStream_t stream) {
    const float* x  = (const float*)d_in[0];
    const float* Wq = (const float*)d_in[1];
    const float* bq = (const float*)d_in[2];
    const float* Wk = (const float*)d_in[3];
    const float* bk = (const float*)d_in[4];
    const float* Wv = (const float*)d_in[5];
    const float* bv = (const float*)d_in[6];
    const float* Wo = (const float*)d_in[7];
    const float* bo = (const float*)d_in[8];
    float* out = (float*)d_out;
    (void)in_sizes; (void)n_in; (void)out_size; (void)ws_size;

    char* ws = (char*)d_ws;
    __hip_bfloat16* xb  = (__hip_bfloat16*)ws;                       // 16 MB
    __hip_bfloat16* Wt3 = (__hip_bfloat16*)(ws + (16u << 20));       // 6 MB (Q,K,V slabs)
    __hip_bfloat16* Wot = (__hip_bfloat16*)(ws + (22u << 20));       // 2 MB
    __hip_bfloat16* Qb  = (__hip_bfloat16*)(ws + (24u << 20));       // 16 MB
    __hip_bfloat16* Kb  = Qb + (size_t)MTOT * DOUT;                  // 16 MB
    __hip_bfloat16* Vtb = Kb + (size_t)MTOT * DOUT;                  // 16 MB (Vff)
    __hip_bfloat16* ctx = xb;  // alias: xb dead after the QKV GEMMs

    cvt_bf16<<<2048, 256, 0, stream>>>((const float4*)x, (ushort4*)xb, MTOT * DIN / 4);

    dim3 tb(32, 8);
    transpose_cvt3<<<dim3(32, 32, 3), tb, 0, stream>>>(Wq, Wk, Wv, Wt3);
    transpose_cvt <<<dim3(32, 32),    tb, 0, stream>>>(Wo, Wot);

    // QK fused GEMM (N=2048, swapped orientation). Q scale folds 1/8 * log2(e).
    dim3 gqk(2*DOUT / 128, MTOT / 128);  // (16, 64)
    gemm_mfma<0><<<gqk, 256, 0, stream>>>(xb, Wt3, bq, bk, Qb, Kb,
                                          0.125f * 1.44269504088896f);
    // V GEMM (N=1024, normal orientation) -> fragment-packed Vff
    dim3 gv(DOUT / 128, MTOT / 128);     // (8, 64)
    gemm_mfma<1><<<gv, 256, 0, stream>>>(xb, Wt3 + (size_t)2*DOUT*DIN, bv, nullptr,
                                         Vtb, nullptr, 1.0f);

    // attn: 64 rows/wave, split-K; grid (bh, pair-group) for XCD L2 locality
    dim3 ag(BSZ * NHEAD, 8);  // (64, 8) = 512 blocks x 4 waves
    attn_fwd<<<ag, 256, 0, stream>>>(Qb, Kb, Vtb, ctx);

    // out-proj (swapped orientation, f32x4 stores)
    gemm_mfma<2><<<gv, 256, 0, stream>>>(ctx, Wot, bo, nullptr,
                                         out, nullptr, 1.0f);
}